// Round 6
// baseline (175.102 us; speedup 1.0000x reference)
//
#include <hip/hip_runtime.h>

// WaveCell FDTD step, fp32, B=8, NY=NX=1024.
// y = inv*(8*h1 - (4-2b)*h2 + c^2*lap),  b = bg + rho/(1+h1^2),
// c = c_linear + 0.01*rho*h1^2, inv = 1/(4+2b), lap = 5pt zero-pad stencil.
// Outputs concatenated: [y (8M floats), h1 copy (8M floats)].
//
// R8: R6 (2 rows/thread burst, best-measured 43 us) with ONE change: the
// XCD row-slice swizzle is removed in favor of flat linear block order.
// R3..R7 showed occupancy (30..65%), per-wave MLP (1x/2x), and wave
// lifetime (burst vs pipelined) ALL tie at ~3.1 TB/s with bytes at floor
// (WRITE = output size exactly; FETCH pinned ~68 MB by harness poisoning).
// Last untested lever vs the 6.3 TB/s copy ubench: global address-walk
// order. Swizzled, the 8 XCDs sweep 8 disjoint strided regions x 6 streams;
// flat, in-flight blocks cover one contiguous window per stream - the
// copy-bench shape, optimal for DRAM page/channel locality. Halo/bg L2
// reuse is sacrificed (cache absorbs it; FETCH may rise a few MB).
// Cache policy unchanged (best measured): nt stores, nt loads h2/cl/rho,
// plain h1/bg.

typedef float f4 __attribute__((ext_vector_type(4)));

#define NX4   256      // float4 per row
#define NYDIM 1024

__device__ __forceinline__ float wave_pt(float h1x, float h2x, float clx,
                                         float rx, float bgx, float lap) {
    float s   = h1x * h1x;
    float b   = bgx + rx * __builtin_amdgcn_rcpf(1.0f + s);
    float c   = clx + 0.01f * rx * s;
    float inv = __builtin_amdgcn_rcpf(4.0f + 2.0f * b);
    return inv * (8.0f * h1x - (4.0f - 2.0f * b) * h2x + c * c * lap);
}

__global__ __launch_bounds__(256, 8) void wavecell_kernel(
    const f4* __restrict__ h1,
    const f4* __restrict__ h2,
    const f4* __restrict__ cl,
    const f4* __restrict__ rho,
    const f4* __restrict__ bg,
    f4*       __restrict__ out,
    int n4)   // total float4 groups = B*NY*NX/4 = 2,097,152
{
    const int tid = threadIdx.x;             // f4-column 0..255
    const int bi  = blockIdx.x;              // 0..4095: one block = row pair
    // FLAT mapping: consecutive blocks -> consecutive row pairs.
    const int rp  = bi & 511;                // row-pair within batch
    const int bat = bi >> 9;                 // batch 0..7
    const int gy0 = rp << 1;                 // even row 0..1022
    const int g0  = (bat << 18) + (gy0 << 8) + tid;
    const int g1  = g0 + NX4;

    const f4 z = {0.f, 0.f, 0.f, 0.f};

    // ---- issue ALL global loads up front (max MLP) ----
    // h1 rows gy0-1 .. gy0+2, register-rolled (plain loads: halo reuse via cache)
    f4 rm1 = (gy0 > 0)           ? h1[g0 - NX4] : z;
    f4 c0  = h1[g0];
    f4 c1  = h1[g1];
    f4 r2  = (gy0 < NYDIM - 2)   ? h1[g1 + NX4] : z;

    // horizontal halo: neighbor lanes' cache lines (L1 hits)
    const float* h1f = (const float*)h1;
    float L0 = (tid > 0)       ? h1f[4 * g0 - 1] : 0.0f;
    float R0 = (tid < NX4 - 1) ? h1f[4 * g0 + 4] : 0.0f;
    float L1 = (tid > 0)       ? h1f[4 * g1 - 1] : 0.0f;
    float R1 = (tid < NX4 - 1) ? h1f[4 * g1 + 4] : 0.0f;

    // stream-once arrays: nontemporal
    f4 h2c0 = __builtin_nontemporal_load(h2 + g0);
    f4 h2c1 = __builtin_nontemporal_load(h2 + g1);
    f4 clc0 = __builtin_nontemporal_load(cl + g0);
    f4 clc1 = __builtin_nontemporal_load(cl + g1);
    f4 rc0  = __builtin_nontemporal_load(rho + g0);
    f4 rc1  = __builtin_nontemporal_load(rho + g1);
    f4 bgc0 = bg[(gy0 << 8) + tid];
    f4 bgc1 = bg[((gy0 + 1) << 8) + tid];

    // ---- row 0: up = rm1, dn = c1 ----
    float lapx0 = rm1.x + c1.x + L0   + c0.y - 4.0f * c0.x;
    float lapy0 = rm1.y + c1.y + c0.x + c0.z - 4.0f * c0.y;
    float lapz0 = rm1.z + c1.z + c0.y + c0.w - 4.0f * c0.z;
    float lapw0 = rm1.w + c1.w + c0.z + R0   - 4.0f * c0.w;

    f4 y0;
    y0.x = wave_pt(c0.x, h2c0.x, clc0.x, rc0.x, bgc0.x, lapx0);
    y0.y = wave_pt(c0.y, h2c0.y, clc0.y, rc0.y, bgc0.y, lapy0);
    y0.z = wave_pt(c0.z, h2c0.z, clc0.z, rc0.z, bgc0.z, lapz0);
    y0.w = wave_pt(c0.w, h2c0.w, clc0.w, rc0.w, bgc0.w, lapw0);

    // ---- row 1: up = c0, dn = r2 ----
    float lapx1 = c0.x + r2.x + L1   + c1.y - 4.0f * c1.x;
    float lapy1 = c0.y + r2.y + c1.x + c1.z - 4.0f * c1.y;
    float lapz1 = c0.z + r2.z + c1.y + c1.w - 4.0f * c1.z;
    float lapw1 = c0.w + r2.w + c1.z + R1   - 4.0f * c1.w;

    f4 y1;
    y1.x = wave_pt(c1.x, h2c1.x, clc1.x, rc1.x, bgc1.x, lapx1);
    y1.y = wave_pt(c1.y, h2c1.y, clc1.y, rc1.y, bgc1.y, lapy1);
    y1.z = wave_pt(c1.z, h2c1.z, clc1.z, rc1.z, bgc1.z, lapz1);
    y1.w = wave_pt(c1.w, h2c1.w, clc1.w, rc1.w, bgc1.w, lapw1);

    __builtin_nontemporal_store(y0, out + g0);        // y row 0
    __builtin_nontemporal_store(y1, out + g1);        // y row 1
    __builtin_nontemporal_store(c0, out + n4 + g0);   // h1 copy row 0
    __builtin_nontemporal_store(c1, out + n4 + g1);   // h1 copy row 1
}

extern "C" void kernel_launch(void* const* d_in, const int* in_sizes, int n_in,
                              void* d_out, int out_size, void* d_ws, size_t ws_size,
                              hipStream_t stream) {
    const f4* h1  = (const f4*)d_in[0];
    const f4* h2  = (const f4*)d_in[1];
    const f4* cl  = (const f4*)d_in[2];
    const f4* rho = (const f4*)d_in[3];
    const f4* bg  = (const f4*)d_in[4];
    f4* out = (f4*)d_out;

    int n  = in_sizes[0];          // 8*1024*1024
    int n4 = n / 4;                // 2,097,152 float4 groups
    // grid: 8 batches x 512 row-pairs = 4096 blocks, flat order
    wavecell_kernel<<<4096, 256, 0, stream>>>(h1, h2, cl, rho, bg, out, n4);
}

// Round 7
// 170.362 us; speedup vs baseline: 1.0278x; 1.0278x over previous
//
#include <hip/hip_runtime.h>

// WaveCell FDTD step, fp32, B=8, NY=NX=1024.
// y = inv*(8*h1 - (4-2b)*h2 + c^2*lap),  b = bg + rho/(1+h1^2),
// c = c_linear + 0.01*rho*h1^2, inv = 1/(4+2b), lap = 5pt zero-pad stencil.
// Outputs concatenated: [y (8M floats), h1 copy (8M floats)].
//
// R9: R6 (2 rows/thread burst, XCD swizzle, 43 us best) with ONE change:
// stores are PLAIN instead of nontemporal. Completes the cache-policy A/B
// matrix (R4/R6 = nt/nt 43us, R5 = plain/plain 60us — confounded by plain
// LOADS thrashing the h1 halo out of L1/L2). Mechanism under test: nt
// stores force 64 MiB of synchronous HBM write-drain inside the kernel
// (WRITE_SIZE = exactly output size every round); plain stores complete at
// L2, absorb into 32 MB aggregate L2 + MALL, drain lazily — and the
// harness's poison pass overwrites out in-place next iteration, so dirty
// output lines may never need HBM writeback at all.
// Loads unchanged: nt for h2/cl/rho (stream-once), plain for h1/bg (reuse).
// XCD swizzle: XCD x owns rows [x*128,(x+1)*128) for all 8 batches.

typedef float f4 __attribute__((ext_vector_type(4)));

#define NX4   256      // float4 per row
#define NYDIM 1024

__device__ __forceinline__ float wave_pt(float h1x, float h2x, float clx,
                                         float rx, float bgx, float lap) {
    float s   = h1x * h1x;
    float b   = bgx + rx * __builtin_amdgcn_rcpf(1.0f + s);
    float c   = clx + 0.01f * rx * s;
    float inv = __builtin_amdgcn_rcpf(4.0f + 2.0f * b);
    return inv * (8.0f * h1x - (4.0f - 2.0f * b) * h2x + c * c * lap);
}

__global__ __launch_bounds__(256, 6) void wavecell_kernel(
    const f4* __restrict__ h1,
    const f4* __restrict__ h2,
    const f4* __restrict__ cl,
    const f4* __restrict__ rho,
    const f4* __restrict__ bg,
    f4*       __restrict__ out,
    int n4)   // total float4 groups = B*NY*NX/4 = 2,097,152
{
    const int tid = threadIdx.x;             // f4-column 0..255
    const int bi  = blockIdx.x;              // 0..4095: one block = row pair
    const int xcd = bi & 7;
    const int j   = bi >> 3;                 // 0..511
    const int rpl = j & 63;                  // row-pair within XCD slice
    const int bat = j >> 6;                  // batch 0..7
    const int gy0 = ((xcd << 6) | rpl) << 1; // even row 0..1022
    const int g0  = (bat << 18) + (gy0 << 8) + tid;
    const int g1  = g0 + NX4;

    const f4 z = {0.f, 0.f, 0.f, 0.f};

    // ---- issue ALL global loads up front (max MLP) ----
    // h1 rows gy0-1 .. gy0+2, register-rolled (plain loads: halo reuse via L2)
    f4 rm1 = (gy0 > 0)           ? h1[g0 - NX4] : z;
    f4 c0  = h1[g0];
    f4 c1  = h1[g1];
    f4 r2  = (gy0 < NYDIM - 2)   ? h1[g1 + NX4] : z;

    // horizontal halo: neighbor lanes' cache lines (L1 hits)
    const float* h1f = (const float*)h1;
    float L0 = (tid > 0)       ? h1f[4 * g0 - 1] : 0.0f;
    float R0 = (tid < NX4 - 1) ? h1f[4 * g0 + 4] : 0.0f;
    float L1 = (tid > 0)       ? h1f[4 * g1 - 1] : 0.0f;
    float R1 = (tid < NX4 - 1) ? h1f[4 * g1 + 4] : 0.0f;

    // stream-once arrays: nontemporal
    f4 h2c0 = __builtin_nontemporal_load(h2 + g0);
    f4 h2c1 = __builtin_nontemporal_load(h2 + g1);
    f4 clc0 = __builtin_nontemporal_load(cl + g0);
    f4 clc1 = __builtin_nontemporal_load(cl + g1);
    f4 rc0  = __builtin_nontemporal_load(rho + g0);
    f4 rc1  = __builtin_nontemporal_load(rho + g1);
    f4 bgc0 = bg[(gy0 << 8) + tid];          // L2-resident slice
    f4 bgc1 = bg[((gy0 + 1) << 8) + tid];

    // ---- row 0: up = rm1, dn = c1 ----
    float lapx0 = rm1.x + c1.x + L0   + c0.y - 4.0f * c0.x;
    float lapy0 = rm1.y + c1.y + c0.x + c0.z - 4.0f * c0.y;
    float lapz0 = rm1.z + c1.z + c0.y + c0.w - 4.0f * c0.z;
    float lapw0 = rm1.w + c1.w + c0.z + R0   - 4.0f * c0.w;

    f4 y0;
    y0.x = wave_pt(c0.x, h2c0.x, clc0.x, rc0.x, bgc0.x, lapx0);
    y0.y = wave_pt(c0.y, h2c0.y, clc0.y, rc0.y, bgc0.y, lapy0);
    y0.z = wave_pt(c0.z, h2c0.z, clc0.z, rc0.z, bgc0.z, lapz0);
    y0.w = wave_pt(c0.w, h2c0.w, clc0.w, rc0.w, bgc0.w, lapw0);

    // ---- row 1: up = c0, dn = r2 ----
    float lapx1 = c0.x + r2.x + L1   + c1.y - 4.0f * c1.x;
    float lapy1 = c0.y + r2.y + c1.x + c1.z - 4.0f * c1.y;
    float lapz1 = c0.z + r2.z + c1.y + c1.w - 4.0f * c1.z;
    float lapw1 = c0.w + r2.w + c1.z + R1   - 4.0f * c1.w;

    f4 y1;
    y1.x = wave_pt(c1.x, h2c1.x, clc1.x, rc1.x, bgc1.x, lapx1);
    y1.y = wave_pt(c1.y, h2c1.y, clc1.y, rc1.y, bgc1.y, lapy1);
    y1.z = wave_pt(c1.z, h2c1.z, clc1.z, rc1.z, bgc1.z, lapz1);
    y1.w = wave_pt(c1.w, h2c1.w, clc1.w, rc1.w, bgc1.w, lapw1);

    // PLAIN stores (the single change vs R6): complete at L2, lazy drain.
    out[g0]      = y0;   // y row 0
    out[g1]      = y1;   // y row 1
    out[n4 + g0] = c0;   // h1 copy row 0
    out[n4 + g1] = c1;   // h1 copy row 1
}

extern "C" void kernel_launch(void* const* d_in, const int* in_sizes, int n_in,
                              void* d_out, int out_size, void* d_ws, size_t ws_size,
                              hipStream_t stream) {
    const f4* h1  = (const f4*)d_in[0];
    const f4* h2  = (const f4*)d_in[1];
    const f4* cl  = (const f4*)d_in[2];
    const f4* rho = (const f4*)d_in[3];
    const f4* bg  = (const f4*)d_in[4];
    f4* out = (f4*)d_out;

    int n  = in_sizes[0];          // 8*1024*1024
    int n4 = n / 4;                // 2,097,152 float4 groups
    // grid: 8 batches x 512 row-pairs = 4096 blocks
    wavecell_kernel<<<4096, 256, 0, stream>>>(h1, h2, cl, rho, bg, out, n4);
}